// Round 7
// baseline (10416.951 us; speedup 1.0000x reference)
//
#include <hip/hip_runtime.h>
#include <hip/hip_bf16.h>

// 2-layer LSTM, B=64, F=128, T=1024, H=512. Output = h_T of layer 1 (64x512 fp32).
// R7: R4 topology (256 WGs x 256 thr, layer-split) + ZERO fences + batched
// L2-bypassing h loads.
//  - h reads: relaxed AGENT-scope u64 atomic loads (proven to bypass L2: R5 passed
//    with no acquire fence). R5's mistake was interleaving load->MFMA so each
//    atomic serialized a full L3 RTT (x16-32). Here ALL loads issue as one burst
//    into locals, pinned by an empty memory-clobber asm, THEN the MFMAs run ->
//    one overlapped RTT. No buffer_inv anywhere: x/weights stay warm in L1/L2
//    across all 1024 iterations (R4's per-iter agent-acquire was a full L2 inv).
//  - __launch_bounds__(256,1): ~280 VGPR budget (L1: 128 weight + 64 h-burst),
//    no spill (R3 lesson), and >=256 VGPR -> 1 wave/SIMD -> no 2-WG/CU packing.
//  - barrier: R4 all-poll (tid0 posts, every thread polls one flag line),
//    syncthreads-drain before post (release), syncthreads after poll. No fence,
//    no trailing inv barrier.
//  - unchanged: 4-gen h rotation, sc0sc1 relaxed-agent publish stores, shfl pack,
//    x prefetch in the wait window, bf16 numerics (absmax 4.88e-4, 4x margin).

#define B_ 64
#define F_ 128
#define T_ 1024
#define H_ 512
#define NWG 256

typedef __bf16 bf16x8 __attribute__((ext_vector_type(8)));
typedef float f32x4 __attribute__((ext_vector_type(4)));
typedef unsigned long long u64;

__device__ __forceinline__ float sigm(float x) { return 1.0f / (1.0f + __expf(-x)); }
__device__ __forceinline__ float tanh_fast(float x) { return 1.0f - 2.0f / (__expf(2.0f * x) + 1.0f); }

__device__ __forceinline__ u64 ld_bypass(const u64* p) {
  return __hip_atomic_load(p, __ATOMIC_RELAXED, __HIP_MEMORY_SCOPE_AGENT);
}
__device__ __forceinline__ bf16x8 to_bf16x8(u64 lo, u64 hi) {
  union { u64 q[2]; bf16x8 v; } u;
  u.q[0] = lo; u.q[1] = hi;
  return u.v;
}

// x (B,F,T) fp32 -> xT (T,B,F) bf16
__global__ __launch_bounds__(256) void transpose_x_kernel(const float* __restrict__ x,
                                                          __bf16* __restrict__ xT) {
  __shared__ float tile[F_][65];
  const int bb = blockIdx.x >> 4;
  const int tt = blockIdx.x & 15;
  const int tid = threadIdx.x;
  const int tl = tid & 63;
  const int f0 = tid >> 6;
  for (int fo = 0; fo < F_; fo += 4) {
    int f = fo + f0;
    tile[f][tl] = x[((size_t)bb * F_ + f) * T_ + tt * 64 + tl];
  }
  __syncthreads();
  const int fw = tid & 127;
  const int tg = tid >> 7;
  for (int to = 0; to < 64; to += 2) {
    int t = to + tg;
    xT[((size_t)(tt * 64 + t) * B_ + bb) * F_ + fw] = (__bf16)tile[fw][t];
  }
}

__global__ __launch_bounds__(256, 1) void lstm_persistent(
    const __bf16* __restrict__ xT,
    const float* __restrict__ Wih0, const float* __restrict__ Whh0,
    const float* __restrict__ bih0, const float* __restrict__ bhh0,
    const float* __restrict__ Wih1, const float* __restrict__ Whh1,
    const float* __restrict__ bih1, const float* __restrict__ bhh1,
    __bf16* h0_pub, __bf16* h1_pub,   // each: [4][B][H] bf16, 4-gen rotation
    unsigned* flags,                   // [NWG] x 64B lines, monotone counters
    float* __restrict__ out) {
  __shared__ float sG[4][272];   // gate reshuffle staging, stride 68 (conflict-free)

  const int wg   = blockIdx.x;
  const int tid  = threadIdx.x;
  const int wv   = tid >> 6;
  const int lane = tid & 63;
  const int p    = lane >> 4;        // quad
  const int l15  = lane & 15;
  const int b    = wv * 16 + l15;    // batch
  const int ks   = p * 8;            // k offset inside a 32-chunk
  const int col4 = (wg & 127) * 4;   // this WG's 4 h-columns
  const int row  = (l15 >> 2) * H_ + col4 + (l15 & 3);  // A-frag gate row for m=l15
  const int base64 = (b * H_ + ks) >> 2;   // u64 index of this lane's h row start

  if (wg < 128) {
    // ---------------- layer 0 ----------------
    bf16x8 wh[16], wi[4];
    {
      const float* s = Whh0 + (size_t)row * H_ + ks;
#pragma unroll
      for (int kc = 0; kc < 16; ++kc) {
        bf16x8 a;
#pragma unroll
        for (int j = 0; j < 8; ++j) a[j] = (__bf16)s[kc * 32 + j];
        wh[kc] = a;
      }
      const float* si = Wih0 + (size_t)row * F_ + ks;
#pragma unroll
      for (int kc = 0; kc < 4; ++kc) {
        bf16x8 a;
#pragma unroll
        for (int j = 0; j < 8; ++j) a[j] = (__bf16)si[kc * 32 + j];
        wi[kc] = a;
      }
    }
    float bq[4];
#pragma unroll
    for (int r = 0; r < 4; ++r) {
      const int grow = p * H_ + col4 + r;
      bq[r] = bih0[grow] + bhh0[grow];
    }

    bf16x8 xb[4];
#pragma unroll
    for (int kc = 0; kc < 4; ++kc)
      xb[kc] = *(const bf16x8*)&xT[(size_t)b * F_ + kc * 32 + ks];

    float c0 = 0.f;
    for (int it = 0; it < T_; ++it) {
      const u64* h0q = (const u64*)(h0_pub + ((it + 3) & 3) * (B_ * H_));
      unsigned* h0w = (unsigned*)(h0_pub + (it & 3) * (B_ * H_));

      // ---- burst: issue ALL h loads, pin, then MFMA ----
      u64 q[32];
#pragma unroll
      for (int kc = 0; kc < 16; ++kc) {
        q[2 * kc]     = ld_bypass(h0q + base64 + kc * 8);
        q[2 * kc + 1] = ld_bypass(h0q + base64 + kc * 8 + 1);
      }
      asm volatile("" ::: "memory");   // loads may not sink below this point

      f32x4 acc  = {0.f, 0.f, 0.f, 0.f};
      f32x4 acc2 = {0.f, 0.f, 0.f, 0.f};
#pragma unroll
      for (int kc = 0; kc < 16; ++kc)
        acc = __builtin_amdgcn_mfma_f32_16x16x32_bf16(
            wh[kc], to_bf16x8(q[2 * kc], q[2 * kc + 1]), acc, 0, 0, 0);
#pragma unroll
      for (int kc = 0; kc < 4; ++kc)
        acc2 = __builtin_amdgcn_mfma_f32_16x16x32_bf16(wi[kc], xb[kc], acc2, 0, 0, 0);

#pragma unroll
      for (int r = 0; r < 4; ++r) {
        float v = acc[r] + acc2[r] + bq[r];
        sG[wv][p * 68 + r * 16 + l15] = (p == 2) ? tanh_fast(v) : sigm(v);
      }
      __syncthreads();
      float gi = sG[wv][0 * 68 + p * 16 + l15];
      float gf = sG[wv][1 * 68 + p * 16 + l15];
      float gg = sG[wv][2 * 68 + p * 16 + l15];
      float go = sG[wv][3 * 68 + p * 16 + l15];
      c0 = gf * c0 + gi * gg;
      float h = go * tanh_fast(c0);

      union { __bf16 bf; unsigned short u; } cv; cv.bf = (__bf16)h;
      unsigned o = (unsigned)__shfl_xor((int)(unsigned)cv.u, 16, 64);
      if ((p & 1) == 0) {
        unsigned v = (unsigned)cv.u | (o << 16);
        __hip_atomic_store(h0w + b * (H_ / 2) + (col4 >> 1) + (p >> 1), v,
                           __ATOMIC_RELAXED, __HIP_MEMORY_SCOPE_AGENT);
      }

      // ---- barrier: drain -> post -> (x prefetch) -> poll -> release ----
      const unsigned tgt = (unsigned)(it + 1);
      __syncthreads();   // s_waitcnt vmcnt(0) before s_barrier: publishes at L3
      if (tid == 0)
        __hip_atomic_store(&flags[wg * 16], tgt, __ATOMIC_RELAXED, __HIP_MEMORY_SCOPE_AGENT);
      if (it + 1 < T_) { // prefetch next x while others arrive (normal cached loads)
        const __bf16* xrow = xT + ((size_t)(it + 1) * B_ + b) * F_;
#pragma unroll
        for (int kc = 0; kc < 4; ++kc) xb[kc] = *(const bf16x8*)&xrow[kc * 32 + ks];
      }
      while (__hip_atomic_load(&flags[tid * 16], __ATOMIC_RELAXED,
                               __HIP_MEMORY_SCOPE_AGENT) < tgt)
        __builtin_amdgcn_s_sleep(1);
      __syncthreads();   // all 256 WGs arrived; next-gen h reads may start
    }
  } else {
    // ---------------- layer 1 ----------------
    bf16x8 wi[16], wh[16];
    {
      const float* s0 = Wih1 + (size_t)row * H_ + ks;
      const float* s1 = Whh1 + (size_t)row * H_ + ks;
#pragma unroll
      for (int kc = 0; kc < 16; ++kc) {
        bf16x8 a, c;
#pragma unroll
        for (int j = 0; j < 8; ++j) {
          a[j] = (__bf16)s0[kc * 32 + j];
          c[j] = (__bf16)s1[kc * 32 + j];
        }
        wi[kc] = a; wh[kc] = c;
      }
    }
    float bq[4];
#pragma unroll
    for (int r = 0; r < 4; ++r) {
      const int grow = p * H_ + col4 + r;
      bq[r] = bih1[grow] + bhh1[grow];
    }

    float c1 = 0.f;
    {  // participate in barrier for it=0 (layer-1 idle that step)
      __syncthreads();
      if (tid == 0)
        __hip_atomic_store(&flags[wg * 16], 1u, __ATOMIC_RELAXED, __HIP_MEMORY_SCOPE_AGENT);
      while (__hip_atomic_load(&flags[tid * 16], __ATOMIC_RELAXED,
                               __HIP_MEMORY_SCOPE_AGENT) < 1u)
        __builtin_amdgcn_s_sleep(1);
      __syncthreads();
    }
    for (int it = 1; it <= T_; ++it) {
      const u64* h0q = (const u64*)(h0_pub + ((it + 3) & 3) * (B_ * H_));
      const u64* h1q = (const u64*)(h1_pub + ((it + 3) & 3) * (B_ * H_));
      unsigned* h1w = (unsigned*)(h1_pub + (it & 3) * (B_ * H_));

      // ---- burst: issue ALL 64 h loads, pin, then MFMA ----
      u64 q0[32], q1[32];
#pragma unroll
      for (int kc = 0; kc < 16; ++kc) {
        q0[2 * kc]     = ld_bypass(h0q + base64 + kc * 8);
        q0[2 * kc + 1] = ld_bypass(h0q + base64 + kc * 8 + 1);
        q1[2 * kc]     = ld_bypass(h1q + base64 + kc * 8);
        q1[2 * kc + 1] = ld_bypass(h1q + base64 + kc * 8 + 1);
      }
      asm volatile("" ::: "memory");   // loads may not sink below this point

      f32x4 acca = {0.f, 0.f, 0.f, 0.f};
      f32x4 accc = {0.f, 0.f, 0.f, 0.f};
#pragma unroll
      for (int kc = 0; kc < 16; ++kc) {
        acca = __builtin_amdgcn_mfma_f32_16x16x32_bf16(
            wi[kc], to_bf16x8(q0[2 * kc], q0[2 * kc + 1]), acca, 0, 0, 0);
        accc = __builtin_amdgcn_mfma_f32_16x16x32_bf16(
            wh[kc], to_bf16x8(q1[2 * kc], q1[2 * kc + 1]), accc, 0, 0, 0);
      }
#pragma unroll
      for (int r = 0; r < 4; ++r) {
        float v = acca[r] + accc[r] + bq[r];
        sG[wv][p * 68 + r * 16 + l15] = (p == 2) ? tanh_fast(v) : sigm(v);
      }
      __syncthreads();
      float gi = sG[wv][0 * 68 + p * 16 + l15];
      float gf = sG[wv][1 * 68 + p * 16 + l15];
      float gg = sG[wv][2 * 68 + p * 16 + l15];
      float go = sG[wv][3 * 68 + p * 16 + l15];
      c1 = gf * c1 + gi * gg;
      float h = go * tanh_fast(c1);

      if (it < T_) {
        union { __bf16 bf; unsigned short u; } cv; cv.bf = (__bf16)h;
        unsigned o = (unsigned)__shfl_xor((int)(unsigned)cv.u, 16, 64);
        if ((p & 1) == 0) {
          unsigned v = (unsigned)cv.u | (o << 16);
          __hip_atomic_store(h1w + b * (H_ / 2) + (col4 >> 1) + (p >> 1), v,
                             __ATOMIC_RELAXED, __HIP_MEMORY_SCOPE_AGENT);
        }
        const unsigned tgt = (unsigned)(it + 1);
        __syncthreads();
        if (tid == 0)
          __hip_atomic_store(&flags[wg * 16], tgt, __ATOMIC_RELAXED, __HIP_MEMORY_SCOPE_AGENT);
        while (__hip_atomic_load(&flags[tid * 16], __ATOMIC_RELAXED,
                                 __HIP_MEMORY_SCOPE_AGENT) < tgt)
          __builtin_amdgcn_s_sleep(1);
        __syncthreads();
      } else {
        out[b * H_ + col4 + p] = h;   // final h1[T-1], fp32
      }
    }
  }
}

// Workspace layout:
//   [0]        flags: 256 x 64B = 16 KiB
//   [16384]    h0_pub: 4 gens x 64x512x2B = 262144 B
//   [278528]   h1_pub: 262144 B
//   [1 MiB]    xT: 16 MiB
// Zeroed region: [0, 540672).
extern "C" void kernel_launch(void* const* d_in, const int* in_sizes, int n_in,
                              void* d_out, int out_size, void* d_ws, size_t ws_size,
                              hipStream_t stream) {
  const float* x    = (const float*)d_in[0];
  const float* Wih0 = (const float*)d_in[1];
  const float* Whh0 = (const float*)d_in[2];
  const float* bih0 = (const float*)d_in[3];
  const float* bhh0 = (const float*)d_in[4];
  const float* Wih1 = (const float*)d_in[5];
  const float* Whh1 = (const float*)d_in[6];
  const float* bih1 = (const float*)d_in[7];
  const float* bhh1 = (const float*)d_in[8];
  float* out = (float*)d_out;

  char* ws = (char*)d_ws;
  unsigned* flags = (unsigned*)ws;
  __bf16* h0p = (__bf16*)(ws + 16384);
  __bf16* h1p = (__bf16*)(ws + 16384 + 4 * B_ * H_ * 2);
  __bf16* xT  = (__bf16*)(ws + (1 << 20));

  hipMemsetAsync(ws, 0, 16384 + 8 * B_ * H_ * 2, stream);

  transpose_x_kernel<<<dim3(B_ * 16), dim3(256), 0, stream>>>(x, xT);

  lstm_persistent<<<dim3(NWG), dim3(256), 0, stream>>>(
      xT, Wih0, Whh0, bih0, bhh0, Wih1, Whh1, bih1, bhh1,
      h0p, h1p, flags, out);
}